// Round 5
// baseline (991.545 us; speedup 1.0000x reference)
//
#include <hip/hip_runtime.h>
#include <math.h>

#define NF 128
#define EPS 1e-5f
#define BNB 1e-4f

static inline int cdiv(int a, int b){ return (a + b - 1) / b; }

typedef __attribute__((ext_vector_type(8))) short bf16x8;
typedef __attribute__((ext_vector_type(4))) float f32x4;

__device__ __forceinline__ float lrelu(float x){ return x > 0.f ? x : 0.2f * x; }
__device__ __forceinline__ float sel4(float4 v, int h){
  float r = v.x;
  r = (h == 1) ? v.y : r;
  r = (h == 2) ? v.z : r;
  r = (h == 3) ? v.w : r;
  return r;
}

// f32 -> bf16 round-to-nearest-even (finite inputs)
__device__ __forceinline__ unsigned short f2b(float f){
  unsigned u = __float_as_uint(f);
  u += 0x7fffu + ((u >> 16) & 1u);
  return (unsigned short)(u >> 16);
}
__device__ __forceinline__ float b2f_lo(unsigned v){ return __uint_as_float(v << 16); }
__device__ __forceinline__ float b2f_hi(unsigned v){ return __uint_as_float(v & 0xffff0000u); }

// ---------------- CSR build: two-level bucket sort ----------------
__global__ void k_zero(float* stats, int* bcnt, int nbkt){
  int i = blockIdx.x * blockDim.x + threadIdx.x;
  if (i < 1024) stats[i] = 0.f;
  if (i < nbkt) bcnt[i] = 0;
}

// coarse histogram over buckets (dst>>8), LDS-aggregated
__global__ __launch_bounds__(256) void k_bhist(const int* __restrict__ ei, int E, int n,
                                               int* __restrict__ bcnt, int nbkt){
  __shared__ int h[256];
  h[threadIdx.x] = 0;
  __syncthreads();
  int total = E + n;
  for (int i = blockIdx.x * 256 + threadIdx.x; i < total; i += gridDim.x * 256){
    int d = (i < E) ? ei[E + i] : (i - E);
    atomicAdd(&h[d >> 8], 1);
  }
  __syncthreads();
  if (threadIdx.x < nbkt && h[threadIdx.x]) atomicAdd(&bcnt[threadIdx.x], h[threadIdx.x]);
}

// 1-block exclusive scan over nbkt (<=256) bucket counts -> boff, bcursor
__global__ __launch_bounds__(256) void k_bscan(const int* __restrict__ bcnt, int* __restrict__ boff,
                                               int* __restrict__ bcursor, int nb){
  int t = threadIdx.x;
  int v = (t < nb) ? bcnt[t] : 0;
  int lane = t & 63, w = t >> 6;
  int x = v;
  #pragma unroll
  for (int d = 1; d < 64; d <<= 1){
    int y = __shfl_up(x, d, 64);
    if (lane >= d) x += y;
  }
  __shared__ int wt[4], wex[4];
  if (lane == 63) wt[w] = x;
  __syncthreads();
  if (t == 0){ int r = 0; for (int i = 0; i < 4; ++i){ wex[i] = r; r += wt[i]; } }
  __syncthreads();
  int ex = wex[w] + x - v;
  if (t < nb){ boff[t] = ex; bcursor[t] = ex; }
  if (t == nb - 1) boff[nb] = ex + v;
}

// coarse scatter: packed entry (s<<8)|(d&255) appended to its bucket (196 moving fronts)
__global__ void k_bscatter(const int* __restrict__ ei, int E, int n,
                           int* __restrict__ bcursor, unsigned* __restrict__ ebuf){
  int i = blockIdx.x * blockDim.x + threadIdx.x;
  int total = E + n;
  if (i >= total) return;
  int s, d;
  if (i < E){ s = ei[i]; d = ei[E + i]; }
  else { s = i - E; d = s; }
  int pos = atomicAdd(&bcursor[d >> 8], 1);
  ebuf[pos] = ((unsigned)s << 8) | (unsigned)(d & 255);
}

// per-bucket degree via LDS histogram (no global atomics)
__global__ __launch_bounds__(256) void k_deg(const unsigned* __restrict__ ebuf,
                                             const int* __restrict__ boff,
                                             int* __restrict__ deg, int n){
  __shared__ int h[256];
  int t = threadIdx.x, b = blockIdx.x;
  h[t] = 0;
  __syncthreads();
  int lo = boff[b], hi = boff[b + 1];
  for (int i = lo + t; i < hi; i += 256) atomicAdd(&h[ebuf[i] & 255u], 1);
  __syncthreads();
  int node = b * 256 + t;
  if (node < n) deg[node] = h[t];
}

// ---- 3-phase multi-block exclusive scan over deg -> off ----
__global__ __launch_bounds__(256) void k_scan1(const int* __restrict__ deg, int* __restrict__ bsum, int n){
  int i = blockIdx.x * 256 + threadIdx.x;
  int v = (i < n) ? deg[i] : 0;
  int lane = threadIdx.x & 63, w = threadIdx.x >> 6;
  int s = v;
  #pragma unroll
  for (int d = 1; d < 64; d <<= 1) s += __shfl_xor(s, d, 64);
  __shared__ int ws_[4];
  if (lane == 0) ws_[w] = s;
  __syncthreads();
  if (threadIdx.x == 0) bsum[blockIdx.x] = ws_[0] + ws_[1] + ws_[2] + ws_[3];
}

__global__ __launch_bounds__(256) void k_scan2(int* __restrict__ bsum, int nb){
  int t = threadIdx.x;
  int v = (t < nb) ? bsum[t] : 0;
  int lane = t & 63, w = t >> 6;
  int x = v;
  #pragma unroll
  for (int d = 1; d < 64; d <<= 1){
    int y = __shfl_up(x, d, 64);
    if (lane >= d) x += y;
  }
  __shared__ int wt[4], wex[4];
  if (lane == 63) wt[w] = x;
  __syncthreads();
  if (t == 0){ int r = 0; for (int i = 0; i < 4; ++i){ wex[i] = r; r += wt[i]; } }
  __syncthreads();
  if (t < nb) bsum[t] = wex[w] + x - v;   // exclusive
}

__global__ __launch_bounds__(256) void k_scan3(const int* __restrict__ deg, const int* __restrict__ bsum,
                                               int* __restrict__ off, int n){
  int i = blockIdx.x * 256 + threadIdx.x;
  int v = (i < n) ? deg[i] : 0;
  int lane = threadIdx.x & 63, w = threadIdx.x >> 6;
  int x = v;
  #pragma unroll
  for (int d = 1; d < 64; d <<= 1){
    int y = __shfl_up(x, d, 64);
    if (lane >= d) x += y;
  }
  __shared__ int wt[4], wex[4];
  if (lane == 63) wt[w] = x;
  __syncthreads();
  if (threadIdx.x == 0){ int r = 0; for (int j = 0; j < 4; ++j){ wex[j] = r; r += wt[j]; } }
  __syncthreads();
  int excl = bsum[blockIdx.x] + wex[w] + (x - v);
  if (i < n) off[i] = excl;
  if (i == n - 1) off[n] = excl + v;
}

// per-bucket fine scatter: rank via LDS atomics, write into L2-resident CSR window
__global__ __launch_bounds__(256) void k_fine(const unsigned* __restrict__ ebuf,
                                              const int* __restrict__ boff,
                                              const int* __restrict__ off,
                                              int* __restrict__ esrc, int n){
  __shared__ int h[256];
  int t = threadIdx.x, b = blockIdx.x;
  h[t] = 0;
  __syncthreads();
  int lo = boff[b], hi = boff[b + 1];
  int base = b * 256;
  for (int i = lo + t; i < hi; i += 256){
    unsigned pk = ebuf[i];
    int ld = (int)(pk & 255u);
    int s  = (int)(pk >> 8);
    int r = atomicAdd(&h[ld], 1);
    esrc[off[base + ld] + r] = s;
  }
}

// ---------------- BN column stats (sum, sumsq into stats[0..127], stats[128..255]) ----------------
__global__ __launch_bounds__(256) void k_colstats(const float* __restrict__ X, int n, float* __restrict__ out){
  __shared__ float ss[4][128], sq[4][128];
  int t = threadIdx.x, lane = t & 63, w = t >> 6;
  float sx = 0.f, sy = 0.f, qx = 0.f, qy = 0.f;
  for (int r = blockIdx.x * 4 + w; r < n; r += gridDim.x * 4){
    float2 v = *(const float2*)(X + (size_t)r * NF + lane * 2);
    sx += v.x; sy += v.y; qx += v.x * v.x; qy += v.y * v.y;
  }
  ss[w][lane * 2] = sx; ss[w][lane * 2 + 1] = sy;
  sq[w][lane * 2] = qx; sq[w][lane * 2 + 1] = qy;
  __syncthreads();
  if (t < 128){
    float tot = ss[0][t] + ss[1][t] + ss[2][t] + ss[3][t];
    atomicAdd(&out[t], tot);
  } else {
    int c = t - 128;
    float tot = sq[0][c] + sq[1][c] + sq[2][c] + sq[3][c];
    atomicAdd(&out[128 + c], tot);
  }
}

// H = (X - m) * rsqrt(var+eps) + BNB   (writes f32 + bf16 copy)
__global__ void k_bnx(const float* __restrict__ X, const float* __restrict__ stats,
                      float* __restrict__ H, ushort4* __restrict__ H16, int n){
  size_t tot4 = (size_t)n * (NF / 4);
  float inv_n = 1.f / (float)n;
  for (size_t i = blockIdx.x * (size_t)blockDim.x + threadIdx.x; i < tot4;
       i += (size_t)gridDim.x * blockDim.x){
    float4 v = ((const float4*)X)[i];
    int c0 = (int)((i * 4) % NF);
    float* vv = (float*)&v;
    #pragma unroll
    for (int j = 0; j < 4; ++j){
      float m = stats[c0 + j] * inv_n;
      float var = stats[128 + c0 + j] * inv_n - m * m;
      vv[j] = (vv[j] - m) * rsqrtf(var + EPS) + BNB;
    }
    ((float4*)H)[i] = v;
    ushort4 b;
    b.x = f2b(v.x); b.y = f2b(v.y); b.z = f2b(v.z); b.w = f2b(v.w);
    H16[i] = b;
  }
}

// H = relu( (Xg - m)*inv + BNB + H )   (writes f32 + bf16 copy)
__global__ void k_bnres(const float* __restrict__ Xg, const float* __restrict__ stats,
                        float* __restrict__ H, ushort4* __restrict__ H16, int n){
  size_t tot4 = (size_t)n * (NF / 4);
  float inv_n = 1.f / (float)n;
  for (size_t i = blockIdx.x * (size_t)blockDim.x + threadIdx.x; i < tot4;
       i += (size_t)gridDim.x * blockDim.x){
    float4 v = ((const float4*)Xg)[i];
    float4 hc = ((const float4*)H)[i];
    int c0 = (int)((i * 4) % NF);
    float* vv = (float*)&v;
    float* hh = (float*)&hc;
    #pragma unroll
    for (int j = 0; j < 4; ++j){
      float m = stats[c0 + j] * inv_n;
      float var = stats[128 + c0 + j] * inv_n - m * m;
      float z = (vv[j] - m) * rsqrtf(var + EPS) + BNB + hh[j];
      hh[j] = fmaxf(z, 0.f);
    }
    ((float4*)H)[i] = hc;
    ushort4 b;
    b.x = f2b(hc.x); b.y = f2b(hc.y); b.z = f2b(hc.z); b.w = f2b(hc.w);
    H16[i] = b;
  }
}

__global__ void k_relu(const float* __restrict__ X, float* __restrict__ H,
                       ushort4* __restrict__ H16, size_t tot4){
  for (size_t i = blockIdx.x * (size_t)blockDim.x + threadIdx.x; i < tot4;
       i += (size_t)gridDim.x * blockDim.x){
    float4 v = ((const float4*)X)[i];
    v.x = fmaxf(v.x, 0.f); v.y = fmaxf(v.y, 0.f);
    v.z = fmaxf(v.z, 0.f); v.w = fmaxf(v.w, 0.f);
    ((float4*)H)[i] = v;
    ushort4 b;
    b.x = f2b(v.x); b.y = f2b(v.y); b.z = f2b(v.z); b.w = f2b(v.w);
    H16[i] = b;
  }
}

// ---------------- weight convert + transpose: Wt[l][n][k] bf16 ----------------
__global__ void k_cvtw(const float* __restrict__ W, unsigned short* __restrict__ Wt){
  int i = blockIdx.x * blockDim.x + threadIdx.x;   // 4*128*128
  int l = i >> 14, rem = i & 16383;
  int k = rem >> 7, nn = rem & 127;
  Wt[(l << 14) + nn * 128 + k] = f2b(W[i]);
}

// ---------------- MFMA GEMM: Y16[n,128] = X16[n,128] @ W (Wt is [n][k] bf16) ----------------
__global__ __launch_bounds__(256) void k_gemm(const unsigned short* __restrict__ X,
                                              const unsigned short* __restrict__ Wt,
                                              unsigned short* __restrict__ Y, int n){
  __shared__ unsigned short sX[64 * 128];    // 16 KB, XOR-swizzled 16B units
  __shared__ unsigned short sW[128 * 128];   // 32 KB, [n][k], XOR-swizzled
  int t = threadIdx.x;
  int rbase = blockIdx.x * 64;
  #pragma unroll
  for (int i = 0; i < 8; ++i){               // stage Wt: 2048 uint4
    int idx = t + 256 * i;
    int rn = idx >> 4, c16 = idx & 15;
    uint4 v = ((const uint4*)Wt)[idx];
    *(uint4*)&sW[rn * 128 + ((c16 ^ (rn & 7)) << 3)] = v;
  }
  #pragma unroll
  for (int i = 0; i < 4; ++i){               // stage X: 1024 uint4
    int idx = t + 256 * i;
    int r = idx >> 4, c16 = idx & 15;
    int gr = rbase + r;
    uint4 v = (gr < n) ? ((const uint4*)(X + (size_t)gr * NF))[c16] : make_uint4(0, 0, 0, 0);
    *(uint4*)&sX[r * 128 + ((c16 ^ (r & 7)) << 3)] = v;
  }
  __syncthreads();
  int lane = t & 63, w = t >> 6;
  int lrow = w * 16 + (lane & 15);
  int khi = lane >> 4;                       // 0..3
  bf16x8 a[4];
  #pragma unroll
  for (int ks = 0; ks < 4; ++ks){
    int c16 = ks * 4 + khi;
    a[ks] = *(const bf16x8*)&sX[lrow * 128 + ((c16 ^ (lrow & 7)) << 3)];
  }
  f32x4 acc[8];
  #pragma unroll
  for (int nt = 0; nt < 8; ++nt){
    f32x4 z = {0.f, 0.f, 0.f, 0.f};
    acc[nt] = z;
    int nrow = nt * 16 + (lane & 15);
    #pragma unroll
    for (int ks = 0; ks < 4; ++ks){
      int c16 = ks * 4 + khi;
      bf16x8 b = *(const bf16x8*)&sW[nrow * 128 + ((c16 ^ (nrow & 7)) << 3)];
      acc[nt] = __builtin_amdgcn_mfma_f32_16x16x32_bf16(a[ks], b, acc[nt], 0, 0, 0);
    }
  }
  #pragma unroll
  for (int nt = 0; nt < 8; ++nt){
    #pragma unroll
    for (int i = 0; i < 4; ++i){
      int r = w * 16 + (khi << 2) + i;
      int c = nt * 16 + (lane & 15);
      int csw = c ^ ((r & 7) << 3);
      sX[r * 128 + csw] = f2b(acc[nt][i]);
    }
  }
  __syncthreads();
  #pragma unroll
  for (int i = 0; i < 4; ++i){
    int idx = t + 256 * i;
    int r = idx >> 4, c16 = idx & 15;
    int gr = rbase + r;
    if (gr < n)
      ((uint4*)(Y + (size_t)gr * NF))[c16] = *(const uint4*)&sX[r * 128 + ((c16 ^ (r & 7)) << 3)];
  }
}

// ---------------- per-node attention coefficients a_s, a_d (bf16 input) ----------------
__global__ __launch_bounds__(256) void k_attvec(const unsigned short* __restrict__ Hm16,
                                                const float* __restrict__ asrc,
                                                const float* __restrict__ adst, float* __restrict__ a_s,
                                                float* __restrict__ a_d, int n){
  int t = threadIdx.x, lane = t & 63, w = t >> 6;
  int r = blockIdx.x * 4 + w;
  if (r >= n) return;
  unsigned v = *(const unsigned*)(Hm16 + (size_t)r * NF + lane * 2);
  float vx = b2f_lo(v), vy = b2f_hi(v);
  float2 us = *(const float2*)(asrc + lane * 2);
  float2 ud = *(const float2*)(adst + lane * 2);
  float ps = vx * us.x + vy * us.y;
  float pd = vx * ud.x + vy * ud.y;
  #pragma unroll
  for (int d = 1; d < 16; d <<= 1){
    ps += __shfl_xor(ps, d, 64);
    pd += __shfl_xor(pd, d, 64);
  }
  if ((lane & 15) == 0){
    int h = lane >> 4;
    a_s[(size_t)r * 4 + h] = ps;
    a_d[(size_t)r * 4 + h] = pd;
  }
}

// ---------------- attention: fused alpha + online softmax + aggregate, bf16 payload ----------------
__global__ __launch_bounds__(256) void k_attn(const unsigned short* __restrict__ Hm16,
                                              const float* __restrict__ a_s,
                                              const float* __restrict__ a_d,
                                              const int* __restrict__ off,
                                              const int* __restrict__ esrc,
                                              const float* __restrict__ bias,
                                              float* __restrict__ Y, int n){
  int t = threadIdx.x, lane = t & 63, w = t >> 6;
  int node = blockIdx.x * 4 + w;
  if (node >= n) return;
  node = __builtin_amdgcn_readfirstlane(node);
  int head = lane >> 4;
  float4 ad4 = ((const float4*)a_d)[node];
  float adh = sel4(ad4, head);
  int lo = off[node], hi = off[node + 1];
  lo = __builtin_amdgcn_readfirstlane(lo);
  hi = __builtin_amdgcn_readfirstlane(hi);
  int fo = lane * 2;
  float m = -3.4e38f, sum = 0.f, ax = 0.f, ay = 0.f;
  for (int e = lo; e < hi; e += 4){
    int e1 = min(e + 1, hi - 1), e2 = min(e + 2, hi - 1), e3 = min(e + 3, hi - 1);
    int s0 = esrc[e], s1 = esrc[e1], s2 = esrc[e2], s3 = esrc[e3];
    float a0 = lrelu(a_s[s0 * 4 + head] + adh);
    float a1 = lrelu(a_s[s1 * 4 + head] + adh);
    float a2 = lrelu(a_s[s2 * 4 + head] + adh);
    float a3 = lrelu(a_s[s3 * 4 + head] + adh);
    unsigned v0 = *(const unsigned*)(Hm16 + (size_t)s0 * NF + fo);
    unsigned v1 = *(const unsigned*)(Hm16 + (size_t)s1 * NF + fo);
    unsigned v2 = *(const unsigned*)(Hm16 + (size_t)s2 * NF + fo);
    unsigned v3 = *(const unsigned*)(Hm16 + (size_t)s3 * NF + fo);
    if (e + 1 >= hi) a1 = -3.4e38f;   // clamped duplicates get weight 0
    if (e + 2 >= hi) a2 = -3.4e38f;
    if (e + 3 >= hi) a3 = -3.4e38f;
    float mm = fmaxf(fmaxf(a0, a1), fmaxf(a2, a3));
    float newm = fmaxf(m, mm);
    float c = __expf(m - newm);
    float w0 = __expf(a0 - newm), w1 = __expf(a1 - newm);
    float w2 = __expf(a2 - newm), w3 = __expf(a3 - newm);
    sum = sum * c + (w0 + w1 + w2 + w3);
    ax = ax * c + w0 * b2f_lo(v0) + w1 * b2f_lo(v1) + w2 * b2f_lo(v2) + w3 * b2f_lo(v3);
    ay = ay * c + w0 * b2f_hi(v0) + w1 * b2f_hi(v1) + w2 * b2f_hi(v2) + w3 * b2f_hi(v3);
    m = newm;
  }
  float inv = 1.f / (sum + 1e-16f);
  float2 b = *(const float2*)(bias + fo);
  float2 r;
  r.x = ax * inv + b.x;
  r.y = ay * inv + b.y;
  *(float2*)(Y + (size_t)node * NF + fo) = r;
}

// ---------------- pooling: batch is sorted; one block per graph ----------------
__global__ __launch_bounds__(256) void k_pool(const float* __restrict__ H, const int* __restrict__ batch,
                                              float* __restrict__ g, int n){
  int gid = blockIdx.x;
  int t = threadIdx.x, lane = t & 63, w = t >> 6;
  int lo = 0, hi = n;
  while (lo < hi){ int mid = (lo + hi) >> 1; if (batch[mid] < gid) lo = mid + 1; else hi = mid; }
  int a = lo, b = n;
  while (a < b){ int mid = (a + b) >> 1; if (batch[mid] < gid + 1) a = mid + 1; else b = mid; }
  float sx = 0.f, sy = 0.f;
  for (int r = lo + w; r < a; r += 4){
    float2 v = *(const float2*)(H + (size_t)r * NF + lane * 2);
    sx += v.x; sy += v.y;
  }
  __shared__ float ss[4][128];
  ss[w][lane * 2] = sx; ss[w][lane * 2 + 1] = sy;
  __syncthreads();
  if (t < 128) g[(size_t)gid * NF + t] = ss[0][t] + ss[1][t] + ss[2][t] + ss[3][t];
}

// ---------------- head: BN -> fc+relu -> BN -> cls -> log_softmax (single block) ----------------
__global__ __launch_bounds__(1024) void k_head(const float* __restrict__ g, const float* __restrict__ fc_w,
                                               const float* __restrict__ fc_b, const float* __restrict__ cls_w,
                                               const float* __restrict__ cls_b, float* __restrict__ out){
  __shared__ float A[128 * 128];
  __shared__ float mbuf[128], ibuf[128];
  __shared__ float logits[256];
  int t = threadIdx.x;
  #pragma unroll
  for (int i = 0; i < 4; ++i)
    ((float4*)A)[t + 1024 * i] = ((const float4*)g)[t + 1024 * i];
  __syncthreads();
  if (t < 128){
    float s = 0.f, q = 0.f;
    for (int r = 0; r < 128; ++r){ float v = A[r * 128 + t]; s += v; q += v * v; }
    float m = s * (1.f / 128.f);
    float var = q * (1.f / 128.f) - m * m;
    mbuf[t] = m; ibuf[t] = rsqrtf(var + EPS);
  }
  __syncthreads();
  #pragma unroll
  for (int i = 0; i < 16; ++i){
    int idx = t + 1024 * i;
    int c = idx & 127;
    A[idx] = (A[idx] - mbuf[c]) * ibuf[c] + BNB;
  }
  __syncthreads();
  int c0 = (t & 31) * 4, r0 = (t >> 5) * 4;
  float o[4][4];
  float4 bb = *(const float4*)(fc_b + c0);
  #pragma unroll
  for (int i = 0; i < 4; ++i){ o[i][0] = bb.x; o[i][1] = bb.y; o[i][2] = bb.z; o[i][3] = bb.w; }
  for (int k = 0; k < 128; ++k){
    float4 wv = *(const float4*)(fc_w + (size_t)k * 128 + c0);
    #pragma unroll
    for (int i = 0; i < 4; ++i){
      float xs = A[(r0 + i) * 128 + k];
      o[i][0] += xs * wv.x; o[i][1] += xs * wv.y;
      o[i][2] += xs * wv.z; o[i][3] += xs * wv.w;
    }
  }
  __syncthreads();
  #pragma unroll
  for (int i = 0; i < 4; ++i)
    #pragma unroll
    for (int j = 0; j < 4; ++j)
      A[(r0 + i) * 128 + c0 + j] = fmaxf(o[i][j], 0.f);
  __syncthreads();
  if (t < 128){
    float s = 0.f, q = 0.f;
    for (int r = 0; r < 128; ++r){ float v = A[r * 128 + t]; s += v; q += v * v; }
    float m = s * (1.f / 128.f);
    float var = q * (1.f / 128.f) - m * m;
    mbuf[t] = m; ibuf[t] = rsqrtf(var + EPS);
  }
  __syncthreads();
  #pragma unroll
  for (int i = 0; i < 16; ++i){
    int idx = t + 1024 * i;
    int c = idx & 127;
    A[idx] = (A[idx] - mbuf[c]) * ibuf[c] + BNB;
  }
  __syncthreads();
  if (t < 256){
    int r = t >> 1, j = t & 1;
    float accv = cls_b[j];
    for (int k = 0; k < 128; ++k) accv += A[r * 128 + k] * cls_w[k * 2 + j];
    logits[t] = accv;
  }
  __syncthreads();
  if (t < 256){
    int r = t >> 1;
    float l0 = logits[r * 2], l1 = logits[r * 2 + 1];
    float mx = fmaxf(l0, l1);
    float lse = mx + logf(__expf(l0 - mx) + __expf(l1 - mx));
    out[t] = logits[t] - lse;
  }
}

extern "C" void kernel_launch(void* const* d_in, const int* in_sizes, int n_in,
                              void* d_out, int out_size, void* d_ws, size_t ws_size,
                              hipStream_t stream){
  const float* x        = (const float*)d_in[0];
  const int*   ei       = (const int*)d_in[1];
  const int*   batch    = (const int*)d_in[2];
  const float* gat_lin  = (const float*)d_in[3];
  const float* att_src  = (const float*)d_in[4];
  const float* att_dst  = (const float*)d_in[5];
  const float* gat_bias = (const float*)d_in[6];
  const float* fc_w     = (const float*)d_in[7];
  const float* fc_b     = (const float*)d_in[8];
  const float* cls_w    = (const float*)d_in[9];
  const float* cls_b    = (const float*)d_in[10];
  float* out = (float*)d_out;
  (void)n_in; (void)out_size; (void)ws_size;

  int N = in_sizes[0] / NF;
  int E = in_sizes[1] / 2;
  int total = E + N;
  int nb = cdiv(N, 256);     // scan blocks == coarse buckets (196 for N=50000)
  int nbkt = nb;

  char* p = (char*)d_ws;
  auto alloc = [&](size_t bytes) -> char* {
    char* r = p;
    p += (bytes + 255) & ~(size_t)255;
    return r;
  };
  int*   deg     = (int*)alloc((size_t)N * 4);
  int*   off     = (int*)alloc((size_t)(N + 1) * 4);
  int*   bsum    = (int*)alloc((size_t)nb * 4);
  int*   bcnt    = (int*)alloc((size_t)nbkt * 4);
  int*   boff    = (int*)alloc((size_t)(nbkt + 1) * 4);
  int*   bcursor = (int*)alloc((size_t)nbkt * 4);
  unsigned* ebuf = (unsigned*)alloc((size_t)total * 4);
  int*   esrc    = (int*)alloc((size_t)total * 4);
  float* stats   = (float*)alloc(4 * 256 * 4);
  float* hbuf    = (float*)alloc((size_t)N * NF * 4);
  unsigned short* hbuf16 = (unsigned short*)alloc((size_t)N * NF * 2);
  unsigned short* tmp16  = (unsigned short*)alloc((size_t)N * NF * 2);
  unsigned short* wbuf16 = (unsigned short*)alloc((size_t)4 * NF * NF * 2);
  float* gout    = (float*)alloc((size_t)N * NF * 4);
  float* a_s     = (float*)alloc((size_t)N * 4 * 4);
  float* a_d     = (float*)alloc((size_t)N * 4 * 4);
  float* gpool   = (float*)alloc(128 * NF * 4);

  // CSR build (two-level bucket sort)
  k_zero<<<8, 256, 0, stream>>>(stats, bcnt, nbkt);
  k_bhist<<<256, 256, 0, stream>>>(ei, E, N, bcnt, nbkt);
  k_bscan<<<1, 256, 0, stream>>>(bcnt, boff, bcursor, nbkt);
  k_bscatter<<<cdiv(total, 256), 256, 0, stream>>>(ei, E, N, bcursor, ebuf);
  k_deg<<<nbkt, 256, 0, stream>>>(ebuf, boff, deg, N);
  k_scan1<<<nb, 256, 0, stream>>>(deg, bsum, N);
  k_scan2<<<1, 256, 0, stream>>>(bsum, nb);
  k_scan3<<<nb, 256, 0, stream>>>(deg, bsum, off, N);
  k_fine<<<nbkt, 256, 0, stream>>>(ebuf, boff, off, esrc, N);
  k_cvtw<<<256, 256, 0, stream>>>(gat_lin, wbuf16);

  k_colstats<<<256, 256, 0, stream>>>(x, N, stats);
  k_bnx<<<1024, 256, 0, stream>>>(x, stats, hbuf, (ushort4*)hbuf16, N);

  for (int L = 0; L < 4; ++L){
    k_gemm<<<cdiv(N, 64), 256, 0, stream>>>(hbuf16, wbuf16 + (size_t)L * NF * NF, tmp16, N);
    k_attvec<<<cdiv(N, 4), 256, 0, stream>>>(tmp16, att_src + (size_t)L * NF, att_dst + (size_t)L * NF,
                                             a_s, a_d, N);
    k_attn<<<cdiv(N, 4), 256, 0, stream>>>(tmp16, a_s, a_d, off, esrc,
                                           gat_bias + (size_t)L * NF, gout, N);
    if (L == 0){
      k_relu<<<1024, 256, 0, stream>>>(gout, hbuf, (ushort4*)hbuf16, (size_t)N * (NF / 4));
    } else {
      k_colstats<<<256, 256, 0, stream>>>(gout, N, stats + L * 256);
      k_bnres<<<1024, 256, 0, stream>>>(gout, stats + L * 256, hbuf, (ushort4*)hbuf16, N);
    }
  }

  k_pool<<<128, 256, 0, stream>>>(hbuf, batch, gpool, N);
  k_head<<<1, 1024, 0, stream>>>(gpool, fc_w, fc_b, cls_w, cls_b, out);
}

// Round 6
// 533.744 us; speedup vs baseline: 1.8577x; 1.8577x over previous
//
#include <hip/hip_runtime.h>
#include <math.h>

#define NF 128
#define EPS 1e-5f
#define BNB 1e-4f

static inline int cdiv(int a, int b){ return (a + b - 1) / b; }

typedef __attribute__((ext_vector_type(8))) short bf16x8;
typedef __attribute__((ext_vector_type(4))) float f32x4;

__device__ __forceinline__ float lrelu(float x){ return x > 0.f ? x : 0.2f * x; }
__device__ __forceinline__ float sel4(float4 v, int h){
  float r = v.x;
  r = (h == 1) ? v.y : r;
  r = (h == 2) ? v.z : r;
  r = (h == 3) ? v.w : r;
  return r;
}

// f32 -> bf16 round-to-nearest-even (finite inputs)
__device__ __forceinline__ unsigned short f2b(float f){
  unsigned u = __float_as_uint(f);
  u += 0x7fffu + ((u >> 16) & 1u);
  return (unsigned short)(u >> 16);
}
__device__ __forceinline__ float b2f_lo(unsigned v){ return __uint_as_float(v << 16); }
__device__ __forceinline__ float b2f_hi(unsigned v){ return __uint_as_float(v & 0xffff0000u); }

// ---------------- CSR build (single-level: 50K cursors => ~17 atomics/address) ----------------
__global__ void k_init(int* deg, float* stats, int n, int statcount){
  int i = blockIdx.x * blockDim.x + threadIdx.x;
  if (i < n) deg[i] = 1;                // self-loop contributes 1
  if (i < statcount) stats[i] = 0.f;
}

__global__ void k_hist(const int* __restrict__ ei, int E, int* __restrict__ deg){
  int e = blockIdx.x * blockDim.x + threadIdx.x;
  if (e < E) atomicAdd(&deg[ei[E + e]], 1);
}

// ---- 3-phase multi-block exclusive scan (thread i <-> element i) ----
__global__ __launch_bounds__(256) void k_scan1(const int* __restrict__ deg, int* __restrict__ bsum, int n){
  int i = blockIdx.x * 256 + threadIdx.x;
  int v = (i < n) ? deg[i] : 0;
  int lane = threadIdx.x & 63, w = threadIdx.x >> 6;
  int s = v;
  #pragma unroll
  for (int d = 1; d < 64; d <<= 1) s += __shfl_xor(s, d, 64);
  __shared__ int ws_[4];
  if (lane == 0) ws_[w] = s;
  __syncthreads();
  if (threadIdx.x == 0) bsum[blockIdx.x] = ws_[0] + ws_[1] + ws_[2] + ws_[3];
}

__global__ __launch_bounds__(256) void k_scan2(int* __restrict__ bsum, int nb){
  int t = threadIdx.x;
  int v = (t < nb) ? bsum[t] : 0;
  int lane = t & 63, w = t >> 6;
  int x = v;
  #pragma unroll
  for (int d = 1; d < 64; d <<= 1){
    int y = __shfl_up(x, d, 64);
    if (lane >= d) x += y;
  }
  __shared__ int wt[4], wex[4];
  if (lane == 63) wt[w] = x;
  __syncthreads();
  if (t == 0){ int r = 0; for (int i = 0; i < 4; ++i){ wex[i] = r; r += wt[i]; } }
  __syncthreads();
  if (t < nb) bsum[t] = wex[w] + x - v;   // exclusive
}

__global__ __launch_bounds__(256) void k_scan3(const int* __restrict__ deg, const int* __restrict__ bsum,
                                               int* __restrict__ off, int* __restrict__ cursor, int n){
  int i = blockIdx.x * 256 + threadIdx.x;
  int v = (i < n) ? deg[i] : 0;
  int lane = threadIdx.x & 63, w = threadIdx.x >> 6;
  int x = v;
  #pragma unroll
  for (int d = 1; d < 64; d <<= 1){
    int y = __shfl_up(x, d, 64);
    if (lane >= d) x += y;
  }
  __shared__ int wt[4], wex[4];
  if (lane == 63) wt[w] = x;
  __syncthreads();
  if (threadIdx.x == 0){ int r = 0; for (int j = 0; j < 4; ++j){ wex[j] = r; r += wt[j]; } }
  __syncthreads();
  int excl = bsum[blockIdx.x] + wex[w] + (x - v);
  if (i < n){ off[i] = excl; cursor[i] = excl; }
  if (i == n - 1) off[n] = excl + v;
}

// scatter: only esrc is written (one random dword stream)
__global__ void k_scatter(const int* __restrict__ ei, int E, int n,
                          int* __restrict__ cursor, int* __restrict__ esrc){
  int i = blockIdx.x * blockDim.x + threadIdx.x;
  int total = E + n;
  if (i >= total) return;
  int s, d;
  if (i < E){ s = ei[i]; d = ei[E + i]; }
  else { s = i - E; d = s; }
  int pos = atomicAdd(&cursor[d], 1);
  esrc[pos] = s;
}

// ---------------- BN column stats (sum, sumsq into stats[0..127], stats[128..255]) ----------------
__global__ __launch_bounds__(256) void k_colstats(const float* __restrict__ X, int n, float* __restrict__ out){
  __shared__ float ss[4][128], sq[4][128];
  int t = threadIdx.x, lane = t & 63, w = t >> 6;
  float sx = 0.f, sy = 0.f, qx = 0.f, qy = 0.f;
  for (int r = blockIdx.x * 4 + w; r < n; r += gridDim.x * 4){
    float2 v = *(const float2*)(X + (size_t)r * NF + lane * 2);
    sx += v.x; sy += v.y; qx += v.x * v.x; qy += v.y * v.y;
  }
  ss[w][lane * 2] = sx; ss[w][lane * 2 + 1] = sy;
  sq[w][lane * 2] = qx; sq[w][lane * 2 + 1] = qy;
  __syncthreads();
  if (t < 128){
    float tot = ss[0][t] + ss[1][t] + ss[2][t] + ss[3][t];
    atomicAdd(&out[t], tot);
  } else {
    int c = t - 128;
    float tot = sq[0][c] + sq[1][c] + sq[2][c] + sq[3][c];
    atomicAdd(&out[128 + c], tot);
  }
}

// H = (X - m) * rsqrt(var+eps) + BNB   (writes f32 + bf16 copy)
__global__ void k_bnx(const float* __restrict__ X, const float* __restrict__ stats,
                      float* __restrict__ H, ushort4* __restrict__ H16, int n){
  size_t tot4 = (size_t)n * (NF / 4);
  float inv_n = 1.f / (float)n;
  for (size_t i = blockIdx.x * (size_t)blockDim.x + threadIdx.x; i < tot4;
       i += (size_t)gridDim.x * blockDim.x){
    float4 v = ((const float4*)X)[i];
    int c0 = (int)((i * 4) % NF);
    float* vv = (float*)&v;
    #pragma unroll
    for (int j = 0; j < 4; ++j){
      float m = stats[c0 + j] * inv_n;
      float var = stats[128 + c0 + j] * inv_n - m * m;
      vv[j] = (vv[j] - m) * rsqrtf(var + EPS) + BNB;
    }
    ((float4*)H)[i] = v;
    ushort4 b;
    b.x = f2b(v.x); b.y = f2b(v.y); b.z = f2b(v.z); b.w = f2b(v.w);
    H16[i] = b;
  }
}

// H = relu( (Xg - m)*inv + BNB + H )   (writes f32 + bf16 copy)
__global__ void k_bnres(const float* __restrict__ Xg, const float* __restrict__ stats,
                        float* __restrict__ H, ushort4* __restrict__ H16, int n){
  size_t tot4 = (size_t)n * (NF / 4);
  float inv_n = 1.f / (float)n;
  for (size_t i = blockIdx.x * (size_t)blockDim.x + threadIdx.x; i < tot4;
       i += (size_t)gridDim.x * blockDim.x){
    float4 v = ((const float4*)Xg)[i];
    float4 hc = ((const float4*)H)[i];
    int c0 = (int)((i * 4) % NF);
    float* vv = (float*)&v;
    float* hh = (float*)&hc;
    #pragma unroll
    for (int j = 0; j < 4; ++j){
      float m = stats[c0 + j] * inv_n;
      float var = stats[128 + c0 + j] * inv_n - m * m;
      float z = (vv[j] - m) * rsqrtf(var + EPS) + BNB + hh[j];
      hh[j] = fmaxf(z, 0.f);
    }
    ((float4*)H)[i] = hc;
    ushort4 b;
    b.x = f2b(hc.x); b.y = f2b(hc.y); b.z = f2b(hc.z); b.w = f2b(hc.w);
    H16[i] = b;
  }
}

__global__ void k_relu(const float* __restrict__ X, float* __restrict__ H,
                       ushort4* __restrict__ H16, size_t tot4){
  for (size_t i = blockIdx.x * (size_t)blockDim.x + threadIdx.x; i < tot4;
       i += (size_t)gridDim.x * blockDim.x){
    float4 v = ((const float4*)X)[i];
    v.x = fmaxf(v.x, 0.f); v.y = fmaxf(v.y, 0.f);
    v.z = fmaxf(v.z, 0.f); v.w = fmaxf(v.w, 0.f);
    ((float4*)H)[i] = v;
    ushort4 b;
    b.x = f2b(v.x); b.y = f2b(v.y); b.z = f2b(v.z); b.w = f2b(v.w);
    H16[i] = b;
  }
}

// ---------------- weight convert + transpose: Wt[l][n][k] bf16 ----------------
__global__ void k_cvtw(const float* __restrict__ W, unsigned short* __restrict__ Wt){
  int i = blockIdx.x * blockDim.x + threadIdx.x;   // 4*128*128
  int l = i >> 14, rem = i & 16383;
  int k = rem >> 7, nn = rem & 127;
  Wt[(l << 14) + nn * 128 + k] = f2b(W[i]);
}

// ---------------- MFMA GEMM: Y16[n,128] = X16[n,128] @ W (Wt is [n][k] bf16) ----------------
__global__ __launch_bounds__(256) void k_gemm(const unsigned short* __restrict__ X,
                                              const unsigned short* __restrict__ Wt,
                                              unsigned short* __restrict__ Y, int n){
  __shared__ unsigned short sX[64 * 128];    // 16 KB, XOR-swizzled 16B units
  __shared__ unsigned short sW[128 * 128];   // 32 KB, [n][k], XOR-swizzled
  int t = threadIdx.x;
  int rbase = blockIdx.x * 64;
  #pragma unroll
  for (int i = 0; i < 8; ++i){               // stage Wt: 2048 uint4
    int idx = t + 256 * i;
    int rn = idx >> 4, c16 = idx & 15;
    uint4 v = ((const uint4*)Wt)[idx];
    *(uint4*)&sW[rn * 128 + ((c16 ^ (rn & 7)) << 3)] = v;
  }
  #pragma unroll
  for (int i = 0; i < 4; ++i){               // stage X: 1024 uint4
    int idx = t + 256 * i;
    int r = idx >> 4, c16 = idx & 15;
    int gr = rbase + r;
    uint4 v = (gr < n) ? ((const uint4*)(X + (size_t)gr * NF))[c16] : make_uint4(0, 0, 0, 0);
    *(uint4*)&sX[r * 128 + ((c16 ^ (r & 7)) << 3)] = v;
  }
  __syncthreads();
  int lane = t & 63, w = t >> 6;
  int lrow = w * 16 + (lane & 15);
  int khi = lane >> 4;                       // 0..3
  bf16x8 a[4];
  #pragma unroll
  for (int ks = 0; ks < 4; ++ks){
    int c16 = ks * 4 + khi;
    a[ks] = *(const bf16x8*)&sX[lrow * 128 + ((c16 ^ (lrow & 7)) << 3)];
  }
  f32x4 acc[8];
  #pragma unroll
  for (int nt = 0; nt < 8; ++nt){
    f32x4 z = {0.f, 0.f, 0.f, 0.f};
    acc[nt] = z;
    int nrow = nt * 16 + (lane & 15);
    #pragma unroll
    for (int ks = 0; ks < 4; ++ks){
      int c16 = ks * 4 + khi;
      bf16x8 b = *(const bf16x8*)&sW[nrow * 128 + ((c16 ^ (nrow & 7)) << 3)];
      acc[nt] = __builtin_amdgcn_mfma_f32_16x16x32_bf16(a[ks], b, acc[nt], 0, 0, 0);
    }
  }
  #pragma unroll
  for (int nt = 0; nt < 8; ++nt){
    #pragma unroll
    for (int i = 0; i < 4; ++i){
      int r = w * 16 + (khi << 2) + i;
      int c = nt * 16 + (lane & 15);
      int csw = c ^ ((r & 7) << 3);
      sX[r * 128 + csw] = f2b(acc[nt][i]);
    }
  }
  __syncthreads();
  #pragma unroll
  for (int i = 0; i < 4; ++i){
    int idx = t + 256 * i;
    int r = idx >> 4, c16 = idx & 15;
    int gr = rbase + r;
    if (gr < n)
      ((uint4*)(Y + (size_t)gr * NF))[c16] = *(const uint4*)&sX[r * 128 + ((c16 ^ (r & 7)) << 3)];
  }
}

// ---------------- per-node attention coefficients a_s, a_d (bf16 input) ----------------
__global__ __launch_bounds__(256) void k_attvec(const unsigned short* __restrict__ Hm16,
                                                const float* __restrict__ asrc,
                                                const float* __restrict__ adst, float* __restrict__ a_s,
                                                float* __restrict__ a_d, int n){
  int t = threadIdx.x, lane = t & 63, w = t >> 6;
  int r = blockIdx.x * 4 + w;
  if (r >= n) return;
  unsigned v = *(const unsigned*)(Hm16 + (size_t)r * NF + lane * 2);
  float vx = b2f_lo(v), vy = b2f_hi(v);
  float2 us = *(const float2*)(asrc + lane * 2);
  float2 ud = *(const float2*)(adst + lane * 2);
  float ps = vx * us.x + vy * us.y;
  float pd = vx * ud.x + vy * ud.y;
  #pragma unroll
  for (int d = 1; d < 16; d <<= 1){
    ps += __shfl_xor(ps, d, 64);
    pd += __shfl_xor(pd, d, 64);
  }
  if ((lane & 15) == 0){
    int h = lane >> 4;
    a_s[(size_t)r * 4 + h] = ps;
    a_d[(size_t)r * 4 + h] = pd;
  }
}

// ---------------- attention: fused alpha + online softmax + aggregate, bf16 payload ----------------
__global__ __launch_bounds__(256) void k_attn(const unsigned short* __restrict__ Hm16,
                                              const float* __restrict__ a_s,
                                              const float* __restrict__ a_d,
                                              const int* __restrict__ off,
                                              const int* __restrict__ esrc,
                                              const float* __restrict__ bias,
                                              float* __restrict__ Y, int n){
  int t = threadIdx.x, lane = t & 63, w = t >> 6;
  int node = blockIdx.x * 4 + w;
  if (node >= n) return;
  node = __builtin_amdgcn_readfirstlane(node);
  int head = lane >> 4;
  float4 ad4 = ((const float4*)a_d)[node];
  float adh = sel4(ad4, head);
  int lo = off[node], hi = off[node + 1];
  lo = __builtin_amdgcn_readfirstlane(lo);
  hi = __builtin_amdgcn_readfirstlane(hi);
  int fo = lane * 2;
  float m = -3.4e38f, sum = 0.f, ax = 0.f, ay = 0.f;
  for (int e = lo; e < hi; e += 4){
    int e1 = min(e + 1, hi - 1), e2 = min(e + 2, hi - 1), e3 = min(e + 3, hi - 1);
    int s0 = esrc[e], s1 = esrc[e1], s2 = esrc[e2], s3 = esrc[e3];
    float a0 = lrelu(a_s[s0 * 4 + head] + adh);
    float a1 = lrelu(a_s[s1 * 4 + head] + adh);
    float a2 = lrelu(a_s[s2 * 4 + head] + adh);
    float a3 = lrelu(a_s[s3 * 4 + head] + adh);
    unsigned v0 = *(const unsigned*)(Hm16 + (size_t)s0 * NF + fo);
    unsigned v1 = *(const unsigned*)(Hm16 + (size_t)s1 * NF + fo);
    unsigned v2 = *(const unsigned*)(Hm16 + (size_t)s2 * NF + fo);
    unsigned v3 = *(const unsigned*)(Hm16 + (size_t)s3 * NF + fo);
    if (e + 1 >= hi) a1 = -3.4e38f;   // clamped duplicates get weight 0
    if (e + 2 >= hi) a2 = -3.4e38f;
    if (e + 3 >= hi) a3 = -3.4e38f;
    float mm = fmaxf(fmaxf(a0, a1), fmaxf(a2, a3));
    float newm = fmaxf(m, mm);
    float c = __expf(m - newm);
    float w0 = __expf(a0 - newm), w1 = __expf(a1 - newm);
    float w2 = __expf(a2 - newm), w3 = __expf(a3 - newm);
    sum = sum * c + (w0 + w1 + w2 + w3);
    ax = ax * c + w0 * b2f_lo(v0) + w1 * b2f_lo(v1) + w2 * b2f_lo(v2) + w3 * b2f_lo(v3);
    ay = ay * c + w0 * b2f_hi(v0) + w1 * b2f_hi(v1) + w2 * b2f_hi(v2) + w3 * b2f_hi(v3);
    m = newm;
  }
  float inv = 1.f / (sum + 1e-16f);
  float2 b = *(const float2*)(bias + fo);
  float2 r;
  r.x = ax * inv + b.x;
  r.y = ay * inv + b.y;
  *(float2*)(Y + (size_t)node * NF + fo) = r;
}

// ---------------- pooling: batch is sorted; one block per graph ----------------
__global__ __launch_bounds__(256) void k_pool(const float* __restrict__ H, const int* __restrict__ batch,
                                              float* __restrict__ g, int n){
  int gid = blockIdx.x;
  int t = threadIdx.x, lane = t & 63, w = t >> 6;
  int lo = 0, hi = n;
  while (lo < hi){ int mid = (lo + hi) >> 1; if (batch[mid] < gid) lo = mid + 1; else hi = mid; }
  int a = lo, b = n;
  while (a < b){ int mid = (a + b) >> 1; if (batch[mid] < gid + 1) a = mid + 1; else b = mid; }
  float sx = 0.f, sy = 0.f;
  for (int r = lo + w; r < a; r += 4){
    float2 v = *(const float2*)(H + (size_t)r * NF + lane * 2);
    sx += v.x; sy += v.y;
  }
  __shared__ float ss[4][128];
  ss[w][lane * 2] = sx; ss[w][lane * 2 + 1] = sy;
  __syncthreads();
  if (t < 128) g[(size_t)gid * NF + t] = ss[0][t] + ss[1][t] + ss[2][t] + ss[3][t];
}

// ---------------- head: BN -> fc+relu -> BN -> cls -> log_softmax (single block) ----------------
__global__ __launch_bounds__(1024) void k_head(const float* __restrict__ g, const float* __restrict__ fc_w,
                                               const float* __restrict__ fc_b, const float* __restrict__ cls_w,
                                               const float* __restrict__ cls_b, float* __restrict__ out){
  __shared__ float A[128 * 128];
  __shared__ float mbuf[128], ibuf[128];
  __shared__ float logits[256];
  int t = threadIdx.x;
  #pragma unroll
  for (int i = 0; i < 4; ++i)
    ((float4*)A)[t + 1024 * i] = ((const float4*)g)[t + 1024 * i];
  __syncthreads();
  if (t < 128){
    float s = 0.f, q = 0.f;
    for (int r = 0; r < 128; ++r){ float v = A[r * 128 + t]; s += v; q += v * v; }
    float m = s * (1.f / 128.f);
    float var = q * (1.f / 128.f) - m * m;
    mbuf[t] = m; ibuf[t] = rsqrtf(var + EPS);
  }
  __syncthreads();
  #pragma unroll
  for (int i = 0; i < 16; ++i){
    int idx = t + 1024 * i;
    int c = idx & 127;
    A[idx] = (A[idx] - mbuf[c]) * ibuf[c] + BNB;
  }
  __syncthreads();
  int c0 = (t & 31) * 4, r0 = (t >> 5) * 4;
  float o[4][4];
  float4 bb = *(const float4*)(fc_b + c0);
  #pragma unroll
  for (int i = 0; i < 4; ++i){ o[i][0] = bb.x; o[i][1] = bb.y; o[i][2] = bb.z; o[i][3] = bb.w; }
  for (int k = 0; k < 128; ++k){
    float4 wv = *(const float4*)(fc_w + (size_t)k * 128 + c0);
    #pragma unroll
    for (int i = 0; i < 4; ++i){
      float xs = A[(r0 + i) * 128 + k];
      o[i][0] += xs * wv.x; o[i][1] += xs * wv.y;
      o[i][2] += xs * wv.z; o[i][3] += xs * wv.w;
    }
  }
  __syncthreads();
  #pragma unroll
  for (int i = 0; i < 4; ++i)
    #pragma unroll
    for (int j = 0; j < 4; ++j)
      A[(r0 + i) * 128 + c0 + j] = fmaxf(o[i][j], 0.f);
  __syncthreads();
  if (t < 128){
    float s = 0.f, q = 0.f;
    for (int r = 0; r < 128; ++r){ float v = A[r * 128 + t]; s += v; q += v * v; }
    float m = s * (1.f / 128.f);
    float var = q * (1.f / 128.f) - m * m;
    mbuf[t] = m; ibuf[t] = rsqrtf(var + EPS);
  }
  __syncthreads();
  #pragma unroll
  for (int i = 0; i < 16; ++i){
    int idx = t + 1024 * i;
    int c = idx & 127;
    A[idx] = (A[idx] - mbuf[c]) * ibuf[c] + BNB;
  }
  __syncthreads();
  if (t < 256){
    int r = t >> 1, j = t & 1;
    float accv = cls_b[j];
    for (int k = 0; k < 128; ++k) accv += A[r * 128 + k] * cls_w[k * 2 + j];
    logits[t] = accv;
  }
  __syncthreads();
  if (t < 256){
    int r = t >> 1;
    float l0 = logits[r * 2], l1 = logits[r * 2 + 1];
    float mx = fmaxf(l0, l1);
    float lse = mx + logf(__expf(l0 - mx) + __expf(l1 - mx));
    out[t] = logits[t] - lse;
  }
}

extern "C" void kernel_launch(void* const* d_in, const int* in_sizes, int n_in,
                              void* d_out, int out_size, void* d_ws, size_t ws_size,
                              hipStream_t stream){
  const float* x        = (const float*)d_in[0];
  const int*   ei       = (const int*)d_in[1];
  const int*   batch    = (const int*)d_in[2];
  const float* gat_lin  = (const float*)d_in[3];
  const float* att_src  = (const float*)d_in[4];
  const float* att_dst  = (const float*)d_in[5];
  const float* gat_bias = (const float*)d_in[6];
  const float* fc_w     = (const float*)d_in[7];
  const float* fc_b     = (const float*)d_in[8];
  const float* cls_w    = (const float*)d_in[9];
  const float* cls_b    = (const float*)d_in[10];
  float* out = (float*)d_out;
  (void)n_in; (void)out_size; (void)ws_size;

  int N = in_sizes[0] / NF;
  int E = in_sizes[1] / 2;
  int total = E + N;
  int nb = cdiv(N, 256);   // scan blocks (196 for N=50000; k_scan2 handles up to 256)

  char* p = (char*)d_ws;
  auto alloc = [&](size_t bytes) -> char* {
    char* r = p;
    p += (bytes + 255) & ~(size_t)255;
    return r;
  };
  int*   deg    = (int*)alloc((size_t)N * 4);
  int*   off    = (int*)alloc((size_t)(N + 1) * 4);
  int*   cursor = (int*)alloc((size_t)N * 4);
  int*   bsum   = (int*)alloc((size_t)nb * 4);
  int*   esrc   = (int*)alloc((size_t)total * 4);
  float* stats  = (float*)alloc(4 * 256 * 4);
  float* hbuf   = (float*)alloc((size_t)N * NF * 4);
  unsigned short* hbuf16 = (unsigned short*)alloc((size_t)N * NF * 2);
  unsigned short* tmp16  = (unsigned short*)alloc((size_t)N * NF * 2);
  unsigned short* wbuf16 = (unsigned short*)alloc((size_t)4 * NF * NF * 2);
  float* gout   = (float*)alloc((size_t)N * NF * 4);
  float* a_s    = (float*)alloc((size_t)N * 4 * 4);
  float* a_d    = (float*)alloc((size_t)N * 4 * 4);
  float* gpool  = (float*)alloc(128 * NF * 4);

  // CSR build (single-level; contention-free 50K cursors)
  k_init<<<cdiv(N, 256), 256, 0, stream>>>(deg, stats, N, 1024);
  k_hist<<<cdiv(E, 256), 256, 0, stream>>>(ei, E, deg);
  k_scan1<<<nb, 256, 0, stream>>>(deg, bsum, N);
  k_scan2<<<1, 256, 0, stream>>>(bsum, nb);
  k_scan3<<<nb, 256, 0, stream>>>(deg, bsum, off, cursor, N);
  k_scatter<<<cdiv(total, 256), 256, 0, stream>>>(ei, E, N, cursor, esrc);
  k_cvtw<<<256, 256, 0, stream>>>(gat_lin, wbuf16);

  k_colstats<<<256, 256, 0, stream>>>(x, N, stats);
  k_bnx<<<1024, 256, 0, stream>>>(x, stats, hbuf, (ushort4*)hbuf16, N);

  for (int L = 0; L < 4; ++L){
    k_gemm<<<cdiv(N, 64), 256, 0, stream>>>(hbuf16, wbuf16 + (size_t)L * NF * NF, tmp16, N);
    k_attvec<<<cdiv(N, 4), 256, 0, stream>>>(tmp16, att_src + (size_t)L * NF, att_dst + (size_t)L * NF,
                                             a_s, a_d, N);
    k_attn<<<cdiv(N, 4), 256, 0, stream>>>(tmp16, a_s, a_d, off, esrc,
                                           gat_bias + (size_t)L * NF, gout, N);
    if (L == 0){
      k_relu<<<1024, 256, 0, stream>>>(gout, hbuf, (ushort4*)hbuf16, (size_t)N * (NF / 4));
    } else {
      k_colstats<<<256, 256, 0, stream>>>(gout, N, stats + L * 256);
      k_bnres<<<1024, 256, 0, stream>>>(gout, stats + L * 256, hbuf, (ushort4*)hbuf16, N);
    }
  }

  k_pool<<<128, 256, 0, stream>>>(hbuf, batch, gpool, N);
  k_head<<<1, 1024, 0, stream>>>(gpool, fc_w, fc_b, cls_w, cls_b, out);
}

// Round 7
// 487.709 us; speedup vs baseline: 2.0331x; 1.0944x over previous
//
#include <hip/hip_runtime.h>
#include <math.h>

#define NF 128
#define EPS 1e-5f
#define BNB 1e-4f
#define CHUNK 8192

static inline int cdiv(int a, int b){ return (a + b - 1) / b; }

typedef __attribute__((ext_vector_type(8))) short bf16x8;
typedef __attribute__((ext_vector_type(4))) float f32x4;

__device__ __forceinline__ float lrelu(float x){ return x > 0.f ? x : 0.2f * x; }
__device__ __forceinline__ float sel4(float4 v, int h){
  float r = v.x;
  r = (h == 1) ? v.y : r;
  r = (h == 2) ? v.z : r;
  r = (h == 3) ? v.w : r;
  return r;
}

// f32 -> bf16 round-to-nearest-even (finite inputs)
__device__ __forceinline__ unsigned short f2b(float f){
  unsigned u = __float_as_uint(f);
  u += 0x7fffu + ((u >> 16) & 1u);
  return (unsigned short)(u >> 16);
}
__device__ __forceinline__ float b2f_lo(unsigned v){ return __uint_as_float(v << 16); }
__device__ __forceinline__ float b2f_hi(unsigned v){ return __uint_as_float(v & 0xffff0000u); }

// ---------------- CSR build: chunked-reservation bucket sort ----------------
__global__ void k_zero(float* stats, int* bcnt, int nbkt){
  int i = blockIdx.x * blockDim.x + threadIdx.x;
  if (i < 1024) stats[i] = 0.f;
  if (i < nbkt) bcnt[i] = 0;
}

// coarse histogram over buckets (dst>>8), LDS-aggregated
__global__ __launch_bounds__(256) void k_bhist(const int* __restrict__ ei, int E, int n,
                                               int* __restrict__ bcnt, int nbkt){
  __shared__ int h[256];
  h[threadIdx.x] = 0;
  __syncthreads();
  int total = E + n;
  for (int i = blockIdx.x * 256 + threadIdx.x; i < total; i += gridDim.x * 256){
    int d = (i < E) ? ei[E + i] : (i - E);
    atomicAdd(&h[d >> 8], 1);
  }
  __syncthreads();
  if (threadIdx.x < nbkt && h[threadIdx.x]) atomicAdd(&bcnt[threadIdx.x], h[threadIdx.x]);
}

// 1-block exclusive scan over nbkt (<=256) bucket counts -> boff, bcursor
__global__ __launch_bounds__(256) void k_bscan(const int* __restrict__ bcnt, int* __restrict__ boff,
                                               int* __restrict__ bcursor, int nb){
  int t = threadIdx.x;
  int v = (t < nb) ? bcnt[t] : 0;
  int lane = t & 63, w = t >> 6;
  int x = v;
  #pragma unroll
  for (int d = 1; d < 64; d <<= 1){
    int y = __shfl_up(x, d, 64);
    if (lane >= d) x += y;
  }
  __shared__ int wt[4], wex[4];
  if (lane == 63) wt[w] = x;
  __syncthreads();
  if (t == 0){ int r = 0; for (int i = 0; i < 4; ++i){ wex[i] = r; r += wt[i]; } }
  __syncthreads();
  int ex = wex[w] + x - v;
  if (t < nb){ boff[t] = ex; bcursor[t] = ex; }
  if (t == nb - 1) boff[nb] = ex + v;
}

// chunked scatter: per block, LDS hist -> one reservation atomic per bucket -> ranked write.
// ~104 blocks x 196 buckets: ~104 atomics/address (parallel chains), writes in ~168B runs.
__global__ __launch_bounds__(256) void k_bscatter2(const int* __restrict__ ei, int E, int n,
                                                   int* __restrict__ bcursor,
                                                   unsigned* __restrict__ ebuf, int nbkt){
  __shared__ int h[256], base[256];
  int t = threadIdx.x;
  int total = E + n;
  int lo = blockIdx.x * CHUNK;
  int hi = min(lo + CHUNK, total);
  h[t] = 0;
  __syncthreads();
  for (int i = lo + t; i < hi; i += 256){
    int d = (i < E) ? ei[E + i] : (i - E);
    atomicAdd(&h[d >> 8], 1);
  }
  __syncthreads();
  int cnt = h[t];
  if (t < nbkt && cnt > 0) base[t] = atomicAdd(&bcursor[t], cnt);
  __syncthreads();
  h[t] = 0;
  __syncthreads();
  for (int i = lo + t; i < hi; i += 256){
    int s, d;
    if (i < E){ s = ei[i]; d = ei[E + i]; }
    else { s = i - E; d = s; }
    int b = d >> 8;
    int r = atomicAdd(&h[b], 1);
    ebuf[base[b] + r] = ((unsigned)s << 8) | (unsigned)(d & 255);
  }
}

// per-bucket degree via LDS histogram (no global atomics; includes self-loops)
__global__ __launch_bounds__(256) void k_deg(const unsigned* __restrict__ ebuf,
                                             const int* __restrict__ boff,
                                             int* __restrict__ deg, int n){
  __shared__ int h[256];
  int t = threadIdx.x, b = blockIdx.x;
  h[t] = 0;
  __syncthreads();
  int lo = boff[b], hi = boff[b + 1];
  for (int i = lo + t; i < hi; i += 256) atomicAdd(&h[ebuf[i] & 255u], 1);
  __syncthreads();
  int node = b * 256 + t;
  if (node < n) deg[node] = h[t];
}

// ---- 3-phase multi-block exclusive scan over deg -> off ----
__global__ __launch_bounds__(256) void k_scan1(const int* __restrict__ deg, int* __restrict__ bsum, int n){
  int i = blockIdx.x * 256 + threadIdx.x;
  int v = (i < n) ? deg[i] : 0;
  int lane = threadIdx.x & 63, w = threadIdx.x >> 6;
  int s = v;
  #pragma unroll
  for (int d = 1; d < 64; d <<= 1) s += __shfl_xor(s, d, 64);
  __shared__ int ws_[4];
  if (lane == 0) ws_[w] = s;
  __syncthreads();
  if (threadIdx.x == 0) bsum[blockIdx.x] = ws_[0] + ws_[1] + ws_[2] + ws_[3];
}

__global__ __launch_bounds__(256) void k_scan2(int* __restrict__ bsum, int nb){
  int t = threadIdx.x;
  int v = (t < nb) ? bsum[t] : 0;
  int lane = t & 63, w = t >> 6;
  int x = v;
  #pragma unroll
  for (int d = 1; d < 64; d <<= 1){
    int y = __shfl_up(x, d, 64);
    if (lane >= d) x += y;
  }
  __shared__ int wt[4], wex[4];
  if (lane == 63) wt[w] = x;
  __syncthreads();
  if (t == 0){ int r = 0; for (int i = 0; i < 4; ++i){ wex[i] = r; r += wt[i]; } }
  __syncthreads();
  if (t < nb) bsum[t] = wex[w] + x - v;   // exclusive
}

__global__ __launch_bounds__(256) void k_scan3(const int* __restrict__ deg, const int* __restrict__ bsum,
                                               int* __restrict__ off, int n){
  int i = blockIdx.x * 256 + threadIdx.x;
  int v = (i < n) ? deg[i] : 0;
  int lane = threadIdx.x & 63, w = threadIdx.x >> 6;
  int x = v;
  #pragma unroll
  for (int d = 1; d < 64; d <<= 1){
    int y = __shfl_up(x, d, 64);
    if (lane >= d) x += y;
  }
  __shared__ int wt[4], wex[4];
  if (lane == 63) wt[w] = x;
  __syncthreads();
  if (threadIdx.x == 0){ int r = 0; for (int j = 0; j < 4; ++j){ wex[j] = r; r += wt[j]; } }
  __syncthreads();
  int excl = bsum[blockIdx.x] + wex[w] + (x - v);
  if (i < n) off[i] = excl;
  if (i == n - 1) off[n] = excl + v;
}

// per-bucket fine scatter: rank via LDS atomics, write into L2-resident CSR window
__global__ __launch_bounds__(256) void k_fine(const unsigned* __restrict__ ebuf,
                                              const int* __restrict__ boff,
                                              const int* __restrict__ off,
                                              int* __restrict__ esrc, int n){
  __shared__ int h[256];
  int t = threadIdx.x, b = blockIdx.x;
  h[t] = 0;
  __syncthreads();
  int lo = boff[b], hi = boff[b + 1];
  int base = b * 256;
  for (int i = lo + t; i < hi; i += 256){
    unsigned pk = ebuf[i];
    int ld = (int)(pk & 255u);
    int s  = (int)(pk >> 8);
    int r = atomicAdd(&h[ld], 1);
    esrc[off[base + ld] + r] = s;
  }
}

// ---------------- BN column stats (sum, sumsq into stats[0..127], stats[128..255]) ----------------
__global__ __launch_bounds__(256) void k_colstats(const float* __restrict__ X, int n, float* __restrict__ out){
  __shared__ float ss[4][128], sq[4][128];
  int t = threadIdx.x, lane = t & 63, w = t >> 6;
  float sx = 0.f, sy = 0.f, qx = 0.f, qy = 0.f;
  for (int r = blockIdx.x * 4 + w; r < n; r += gridDim.x * 4){
    float2 v = *(const float2*)(X + (size_t)r * NF + lane * 2);
    sx += v.x; sy += v.y; qx += v.x * v.x; qy += v.y * v.y;
  }
  ss[w][lane * 2] = sx; ss[w][lane * 2 + 1] = sy;
  sq[w][lane * 2] = qx; sq[w][lane * 2 + 1] = qy;
  __syncthreads();
  if (t < 128){
    float tot = ss[0][t] + ss[1][t] + ss[2][t] + ss[3][t];
    atomicAdd(&out[t], tot);
  } else {
    int c = t - 128;
    float tot = sq[0][c] + sq[1][c] + sq[2][c] + sq[3][c];
    atomicAdd(&out[128 + c], tot);
  }
}

// H = (X - m) * rsqrt(var+eps) + BNB   (writes f32 + bf16 copy)
__global__ void k_bnx(const float* __restrict__ X, const float* __restrict__ stats,
                      float* __restrict__ H, ushort4* __restrict__ H16, int n){
  size_t tot4 = (size_t)n * (NF / 4);
  float inv_n = 1.f / (float)n;
  for (size_t i = blockIdx.x * (size_t)blockDim.x + threadIdx.x; i < tot4;
       i += (size_t)gridDim.x * blockDim.x){
    float4 v = ((const float4*)X)[i];
    int c0 = (int)((i * 4) % NF);
    float* vv = (float*)&v;
    #pragma unroll
    for (int j = 0; j < 4; ++j){
      float m = stats[c0 + j] * inv_n;
      float var = stats[128 + c0 + j] * inv_n - m * m;
      vv[j] = (vv[j] - m) * rsqrtf(var + EPS) + BNB;
    }
    ((float4*)H)[i] = v;
    ushort4 b;
    b.x = f2b(v.x); b.y = f2b(v.y); b.z = f2b(v.z); b.w = f2b(v.w);
    H16[i] = b;
  }
}

// H = relu( (Xg - m)*inv + BNB + H )   (writes f32 + bf16 copy)
__global__ void k_bnres(const float* __restrict__ Xg, const float* __restrict__ stats,
                        float* __restrict__ H, ushort4* __restrict__ H16, int n){
  size_t tot4 = (size_t)n * (NF / 4);
  float inv_n = 1.f / (float)n;
  for (size_t i = blockIdx.x * (size_t)blockDim.x + threadIdx.x; i < tot4;
       i += (size_t)gridDim.x * blockDim.x){
    float4 v = ((const float4*)Xg)[i];
    float4 hc = ((const float4*)H)[i];
    int c0 = (int)((i * 4) % NF);
    float* vv = (float*)&v;
    float* hh = (float*)&hc;
    #pragma unroll
    for (int j = 0; j < 4; ++j){
      float m = stats[c0 + j] * inv_n;
      float var = stats[128 + c0 + j] * inv_n - m * m;
      float z = (vv[j] - m) * rsqrtf(var + EPS) + BNB + hh[j];
      hh[j] = fmaxf(z, 0.f);
    }
    ((float4*)H)[i] = hc;
    ushort4 b;
    b.x = f2b(hc.x); b.y = f2b(hc.y); b.z = f2b(hc.z); b.w = f2b(hc.w);
    H16[i] = b;
  }
}

__global__ void k_relu(const float* __restrict__ X, float* __restrict__ H,
                       ushort4* __restrict__ H16, size_t tot4){
  for (size_t i = blockIdx.x * (size_t)blockDim.x + threadIdx.x; i < tot4;
       i += (size_t)gridDim.x * blockDim.x){
    float4 v = ((const float4*)X)[i];
    v.x = fmaxf(v.x, 0.f); v.y = fmaxf(v.y, 0.f);
    v.z = fmaxf(v.z, 0.f); v.w = fmaxf(v.w, 0.f);
    ((float4*)H)[i] = v;
    ushort4 b;
    b.x = f2b(v.x); b.y = f2b(v.y); b.z = f2b(v.z); b.w = f2b(v.w);
    H16[i] = b;
  }
}

// ---------------- weight convert + transpose: Wt[l][n][k] bf16 ----------------
__global__ void k_cvtw(const float* __restrict__ W, unsigned short* __restrict__ Wt){
  int i = blockIdx.x * blockDim.x + threadIdx.x;   // 4*128*128
  int l = i >> 14, rem = i & 16383;
  int k = rem >> 7, nn = rem & 127;
  Wt[(l << 14) + nn * 128 + k] = f2b(W[i]);
}

// ---------------- MFMA GEMM + fused att-vec epilogue ----------------
// Y16[n,128] = X16[n,128] @ W; then a_s/a_d per row from LDS-staged output.
__global__ __launch_bounds__(256) void k_gemm(const unsigned short* __restrict__ X,
                                              const unsigned short* __restrict__ Wt,
                                              unsigned short* __restrict__ Y,
                                              const float* __restrict__ asrc,
                                              const float* __restrict__ adst,
                                              float* __restrict__ a_s,
                                              float* __restrict__ a_d, int n){
  __shared__ unsigned short sX[64 * 128];    // 16 KB, XOR-swizzled 16B units
  __shared__ unsigned short sW[128 * 128];   // 32 KB, [n][k], XOR-swizzled
  int t = threadIdx.x;
  int rbase = blockIdx.x * 64;
  #pragma unroll
  for (int i = 0; i < 8; ++i){               // stage Wt: 2048 uint4
    int idx = t + 256 * i;
    int rn = idx >> 4, c16 = idx & 15;
    uint4 v = ((const uint4*)Wt)[idx];
    *(uint4*)&sW[rn * 128 + ((c16 ^ (rn & 7)) << 3)] = v;
  }
  #pragma unroll
  for (int i = 0; i < 4; ++i){               // stage X: 1024 uint4
    int idx = t + 256 * i;
    int r = idx >> 4, c16 = idx & 15;
    int gr = rbase + r;
    uint4 v = (gr < n) ? ((const uint4*)(X + (size_t)gr * NF))[c16] : make_uint4(0, 0, 0, 0);
    *(uint4*)&sX[r * 128 + ((c16 ^ (r & 7)) << 3)] = v;
  }
  __syncthreads();
  int lane = t & 63, w = t >> 6;
  int lrow = w * 16 + (lane & 15);
  int khi = lane >> 4;                       // 0..3
  bf16x8 a[4];
  #pragma unroll
  for (int ks = 0; ks < 4; ++ks){
    int c16 = ks * 4 + khi;
    a[ks] = *(const bf16x8*)&sX[lrow * 128 + ((c16 ^ (lrow & 7)) << 3)];
  }
  f32x4 acc[8];
  #pragma unroll
  for (int nt = 0; nt < 8; ++nt){
    f32x4 z = {0.f, 0.f, 0.f, 0.f};
    acc[nt] = z;
    int nrow = nt * 16 + (lane & 15);
    #pragma unroll
    for (int ks = 0; ks < 4; ++ks){
      int c16 = ks * 4 + khi;
      bf16x8 b = *(const bf16x8*)&sW[nrow * 128 + ((c16 ^ (nrow & 7)) << 3)];
      acc[nt] = __builtin_amdgcn_mfma_f32_16x16x32_bf16(a[ks], b, acc[nt], 0, 0, 0);
    }
  }
  // stage D (bf16, swizzled) back into sX
  #pragma unroll
  for (int nt = 0; nt < 8; ++nt){
    #pragma unroll
    for (int i = 0; i < 4; ++i){
      int r = w * 16 + (khi << 2) + i;
      int c = nt * 16 + (lane & 15);
      int csw = c ^ ((r & 7) << 3);
      sX[r * 128 + csw] = f2b(acc[nt][i]);
    }
  }
  __syncthreads();
  // coalesced Y store
  #pragma unroll
  for (int i = 0; i < 4; ++i){
    int idx = t + 256 * i;
    int r = idx >> 4, c16 = idx & 15;
    int gr = rbase + r;
    if (gr < n)
      ((uint4*)(Y + (size_t)gr * NF))[c16] = *(const uint4*)&sX[r * 128 + ((c16 ^ (r & 7)) << 3)];
  }
  // fused att-vec: thread -> (row = t>>2, head = t&3); dot 32 elems from LDS
  int r = t >> 2, hh = t & 3;
  int gr = rbase + r;
  if (gr < n){
    float ps = 0.f, pd = 0.f;
    #pragma unroll
    for (int j = 0; j < 16; ++j){
      int c = hh * 32 + j * 2;
      int u = (c >> 3) ^ (r & 7);
      unsigned v = *(const unsigned*)&sX[r * 128 + (u << 3) + (c & 7)];
      float vx = b2f_lo(v), vy = b2f_hi(v);
      ps += vx * asrc[c] + vy * asrc[c + 1];
      pd += vx * adst[c] + vy * adst[c + 1];
    }
    a_s[(size_t)gr * 4 + hh] = ps;
    a_d[(size_t)gr * 4 + hh] = pd;
  }
}

// ---------------- attention: fused alpha + online softmax + aggregate, bf16 payload ----------------
__global__ __launch_bounds__(256) void k_attn(const unsigned short* __restrict__ Hm16,
                                              const float* __restrict__ a_s,
                                              const float* __restrict__ a_d,
                                              const int* __restrict__ off,
                                              const int* __restrict__ esrc,
                                              const float* __restrict__ bias,
                                              float* __restrict__ Y, int n){
  int t = threadIdx.x, lane = t & 63, w = t >> 6;
  int node = blockIdx.x * 4 + w;
  if (node >= n) return;
  node = __builtin_amdgcn_readfirstlane(node);
  int head = lane >> 4;
  float4 ad4 = ((const float4*)a_d)[node];
  float adh = sel4(ad4, head);
  int lo = off[node], hi = off[node + 1];
  lo = __builtin_amdgcn_readfirstlane(lo);
  hi = __builtin_amdgcn_readfirstlane(hi);
  int fo = lane * 2;
  float m = -3.4e38f, sum = 0.f, ax = 0.f, ay = 0.f;
  for (int e = lo; e < hi; e += 4){
    int e1 = min(e + 1, hi - 1), e2 = min(e + 2, hi - 1), e3 = min(e + 3, hi - 1);
    int s0 = esrc[e], s1 = esrc[e1], s2 = esrc[e2], s3 = esrc[e3];
    float a0 = lrelu(a_s[s0 * 4 + head] + adh);
    float a1 = lrelu(a_s[s1 * 4 + head] + adh);
    float a2 = lrelu(a_s[s2 * 4 + head] + adh);
    float a3 = lrelu(a_s[s3 * 4 + head] + adh);
    unsigned v0 = *(const unsigned*)(Hm16 + (size_t)s0 * NF + fo);
    unsigned v1 = *(const unsigned*)(Hm16 + (size_t)s1 * NF + fo);
    unsigned v2 = *(const unsigned*)(Hm16 + (size_t)s2 * NF + fo);
    unsigned v3 = *(const unsigned*)(Hm16 + (size_t)s3 * NF + fo);
    if (e + 1 >= hi) a1 = -3.4e38f;   // clamped duplicates get weight 0
    if (e + 2 >= hi) a2 = -3.4e38f;
    if (e + 3 >= hi) a3 = -3.4e38f;
    float mm = fmaxf(fmaxf(a0, a1), fmaxf(a2, a3));
    float newm = fmaxf(m, mm);
    float c = __expf(m - newm);
    float w0 = __expf(a0 - newm), w1 = __expf(a1 - newm);
    float w2 = __expf(a2 - newm), w3 = __expf(a3 - newm);
    sum = sum * c + (w0 + w1 + w2 + w3);
    ax = ax * c + w0 * b2f_lo(v0) + w1 * b2f_lo(v1) + w2 * b2f_lo(v2) + w3 * b2f_lo(v3);
    ay = ay * c + w0 * b2f_hi(v0) + w1 * b2f_hi(v1) + w2 * b2f_hi(v2) + w3 * b2f_hi(v3);
    m = newm;
  }
  float inv = 1.f / (sum + 1e-16f);
  float2 b = *(const float2*)(bias + fo);
  float2 r;
  r.x = ax * inv + b.x;
  r.y = ay * inv + b.y;
  *(float2*)(Y + (size_t)node * NF + fo) = r;
}

// ---------------- pooling: batch is sorted; one block per graph ----------------
__global__ __launch_bounds__(256) void k_pool(const float* __restrict__ H, const int* __restrict__ batch,
                                              float* __restrict__ g, int n){
  int gid = blockIdx.x;
  int t = threadIdx.x, lane = t & 63, w = t >> 6;
  int lo = 0, hi = n;
  while (lo < hi){ int mid = (lo + hi) >> 1; if (batch[mid] < gid) lo = mid + 1; else hi = mid; }
  int a = lo, b = n;
  while (a < b){ int mid = (a + b) >> 1; if (batch[mid] < gid + 1) a = mid + 1; else b = mid; }
  float sx = 0.f, sy = 0.f;
  for (int r = lo + w; r < a; r += 4){
    float2 v = *(const float2*)(H + (size_t)r * NF + lane * 2);
    sx += v.x; sy += v.y;
  }
  __shared__ float ss[4][128];
  ss[w][lane * 2] = sx; ss[w][lane * 2 + 1] = sy;
  __syncthreads();
  if (t < 128) g[(size_t)gid * NF + t] = ss[0][t] + ss[1][t] + ss[2][t] + ss[3][t];
}

// ---------------- head: BN -> fc+relu -> BN -> cls -> log_softmax (single block) ----------------
__global__ __launch_bounds__(1024) void k_head(const float* __restrict__ g, const float* __restrict__ fc_w,
                                               const float* __restrict__ fc_b, const float* __restrict__ cls_w,
                                               const float* __restrict__ cls_b, float* __restrict__ out){
  __shared__ float A[128 * 128];
  __shared__ float mbuf[128], ibuf[128];
  __shared__ float logits[256];
  int t = threadIdx.x;
  #pragma unroll
  for (int i = 0; i < 4; ++i)
    ((float4*)A)[t + 1024 * i] = ((const float4*)g)[t + 1024 * i];
  __syncthreads();
  if (t < 128){
    float s = 0.f, q = 0.f;
    for (int r = 0; r < 128; ++r){ float v = A[r * 128 + t]; s += v; q += v * v; }
    float m = s * (1.f / 128.f);
    float var = q * (1.f / 128.f) - m * m;
    mbuf[t] = m; ibuf[t] = rsqrtf(var + EPS);
  }
  __syncthreads();
  #pragma unroll
  for (int i = 0; i < 16; ++i){
    int idx = t + 1024 * i;
    int c = idx & 127;
    A[idx] = (A[idx] - mbuf[c]) * ibuf[c] + BNB;
  }
  __syncthreads();
  int c0 = (t & 31) * 4, r0 = (t >> 5) * 4;
  float o[4][4];
  float4 bb = *(const float4*)(fc_b + c0);
  #pragma unroll
  for (int i = 0; i < 4; ++i){ o[i][0] = bb.x; o[i][1] = bb.y; o[i][2] = bb.z; o[i][3] = bb.w; }
  for (int k = 0; k < 128; ++k){
    float4 wv = *(const float4*)(fc_w + (size_t)k * 128 + c0);
    #pragma unroll
    for (int i = 0; i < 4; ++i){
      float xs = A[(r0 + i) * 128 + k];
      o[i][0] += xs * wv.x; o[i][1] += xs * wv.y;
      o[i][2] += xs * wv.z; o[i][3] += xs * wv.w;
    }
  }
  __syncthreads();
  #pragma unroll
  for (int i = 0; i < 4; ++i)
    #pragma unroll
    for (int j = 0; j < 4; ++j)
      A[(r0 + i) * 128 + c0 + j] = fmaxf(o[i][j], 0.f);
  __syncthreads();
  if (t < 128){
    float s = 0.f, q = 0.f;
    for (int r = 0; r < 128; ++r){ float v = A[r * 128 + t]; s += v; q += v * v; }
    float m = s * (1.f / 128.f);
    float var = q * (1.f / 128.f) - m * m;
    mbuf[t] = m; ibuf[t] = rsqrtf(var + EPS);
  }
  __syncthreads();
  #pragma unroll
  for (int i = 0; i < 16; ++i){
    int idx = t + 1024 * i;
    int c = idx & 127;
    A[idx] = (A[idx] - mbuf[c]) * ibuf[c] + BNB;
  }
  __syncthreads();
  if (t < 256){
    int r = t >> 1, j = t & 1;
    float accv = cls_b[j];
    for (int k = 0; k < 128; ++k) accv += A[r * 128 + k] * cls_w[k * 2 + j];
    logits[t] = accv;
  }
  __syncthreads();
  if (t < 256){
    int r = t >> 1;
    float l0 = logits[r * 2], l1 = logits[r * 2 + 1];
    float mx = fmaxf(l0, l1);
    float lse = mx + logf(__expf(l0 - mx) + __expf(l1 - mx));
    out[t] = logits[t] - lse;
  }
}

extern "C" void kernel_launch(void* const* d_in, const int* in_sizes, int n_in,
                              void* d_out, int out_size, void* d_ws, size_t ws_size,
                              hipStream_t stream){
  const float* x        = (const float*)d_in[0];
  const int*   ei       = (const int*)d_in[1];
  const int*   batch    = (const int*)d_in[2];
  const float* gat_lin  = (const float*)d_in[3];
  const float* att_src  = (const float*)d_in[4];
  const float* att_dst  = (const float*)d_in[5];
  const float* gat_bias = (const float*)d_in[6];
  const float* fc_w     = (const float*)d_in[7];
  const float* fc_b     = (const float*)d_in[8];
  const float* cls_w    = (const float*)d_in[9];
  const float* cls_b    = (const float*)d_in[10];
  float* out = (float*)d_out;
  (void)n_in; (void)out_size; (void)ws_size;

  int N = in_sizes[0] / NF;
  int E = in_sizes[1] / 2;
  int total = E + N;
  int nb = cdiv(N, 256);     // scan blocks == coarse buckets (196 for N=50000)
  int nbkt = nb;

  char* p = (char*)d_ws;
  auto alloc = [&](size_t bytes) -> char* {
    char* r = p;
    p += (bytes + 255) & ~(size_t)255;
    return r;
  };
  int*   deg     = (int*)alloc((size_t)N * 4);
  int*   off     = (int*)alloc((size_t)(N + 1) * 4);
  int*   bsum    = (int*)alloc((size_t)nb * 4);
  int*   bcnt    = (int*)alloc((size_t)nbkt * 4);
  int*   boff    = (int*)alloc((size_t)(nbkt + 1) * 4);
  int*   bcursor = (int*)alloc((size_t)nbkt * 4);
  unsigned* ebuf = (unsigned*)alloc((size_t)total * 4);
  int*   esrc    = (int*)alloc((size_t)total * 4);
  float* stats   = (float*)alloc(4 * 256 * 4);
  float* hbuf    = (float*)alloc((size_t)N * NF * 4);
  unsigned short* hbuf16 = (unsigned short*)alloc((size_t)N * NF * 2);
  unsigned short* tmp16  = (unsigned short*)alloc((size_t)N * NF * 2);
  unsigned short* wbuf16 = (unsigned short*)alloc((size_t)4 * NF * NF * 2);
  float* gout    = (float*)alloc((size_t)N * NF * 4);
  float* a_s     = (float*)alloc((size_t)N * 4 * 4);
  float* a_d     = (float*)alloc((size_t)N * 4 * 4);
  float* gpool   = (float*)alloc(128 * NF * 4);

  // CSR build: chunked-reservation bucket sort
  k_zero<<<8, 256, 0, stream>>>(stats, bcnt, nbkt);
  k_bhist<<<256, 256, 0, stream>>>(ei, E, N, bcnt, nbkt);
  k_bscan<<<1, 256, 0, stream>>>(bcnt, boff, bcursor, nbkt);
  k_bscatter2<<<cdiv(total, CHUNK), 256, 0, stream>>>(ei, E, N, bcursor, ebuf, nbkt);
  k_deg<<<nbkt, 256, 0, stream>>>(ebuf, boff, deg, N);
  k_scan1<<<nb, 256, 0, stream>>>(deg, bsum, N);
  k_scan2<<<1, 256, 0, stream>>>(bsum, nb);
  k_scan3<<<nb, 256, 0, stream>>>(deg, bsum, off, N);
  k_fine<<<nbkt, 256, 0, stream>>>(ebuf, boff, off, esrc, N);
  k_cvtw<<<256, 256, 0, stream>>>(gat_lin, wbuf16);

  k_colstats<<<256, 256, 0, stream>>>(x, N, stats);
  k_bnx<<<1024, 256, 0, stream>>>(x, stats, hbuf, (ushort4*)hbuf16, N);

  for (int L = 0; L < 4; ++L){
    k_gemm<<<cdiv(N, 64), 256, 0, stream>>>(hbuf16, wbuf16 + (size_t)L * NF * NF, tmp16,
                                            att_src + (size_t)L * NF, att_dst + (size_t)L * NF,
                                            a_s, a_d, N);
    k_attn<<<cdiv(N, 4), 256, 0, stream>>>(tmp16, a_s, a_d, off, esrc,
                                           gat_bias + (size_t)L * NF, gout, N);
    if (L == 0){
      k_relu<<<1024, 256, 0, stream>>>(gout, hbuf, (ushort4*)hbuf16, (size_t)N * (NF / 4));
    } else {
      k_colstats<<<256, 256, 0, stream>>>(gout, N, stats + L * 256);
      k_bnres<<<1024, 256, 0, stream>>>(gout, stats + L * 256, hbuf, (ushort4*)hbuf16, N);
    }
  }

  k_pool<<<128, 256, 0, stream>>>(hbuf, batch, gpool, N);
  k_head<<<1, 1024, 0, stream>>>(gpool, fc_w, fc_b, cls_w, cls_b, out);
}